// Round 16
// baseline (114.531 us; speedup 1.0000x reference)
//
#include <hip/hip_runtime.h>
#include <hip/hip_bf16.h>
#include <stdint.h>

#define S_LEN  2048
#define HIDDEN 2048
#define NH     32
#define NKVH   8
#define HD     64
#define NHD    (NH*HD)    // 2048
#define KVD    (NKVH*HD)  // 512

typedef __attribute__((ext_vector_type(8))) short  short8;
typedef __attribute__((ext_vector_type(4))) short  short4v;
typedef __attribute__((ext_vector_type(4))) float  f32x4;
typedef __attribute__((ext_vector_type(4))) float  float4v;
typedef __attribute__((ext_vector_type(8))) __bf16 bf16x8;

// counted waits + barriers with memory clobber (rule #18 analog).
#define WAITVM8()  asm volatile("s_waitcnt vmcnt(8)" ::: "memory")
#define WAITVM6()  asm volatile("s_waitcnt vmcnt(6)" ::: "memory")
#define WAITVM4()  asm volatile("s_waitcnt vmcnt(4)" ::: "memory")
#define WAITVM3()  asm volatile("s_waitcnt vmcnt(3)" ::: "memory")
#define WAITVM0()  asm volatile("s_waitcnt vmcnt(0)" ::: "memory")
#define ABARRIER() asm volatile("s_barrier" ::: "memory")

__device__ __forceinline__ short f2bf(float x){
  uint32_t u = __builtin_bit_cast(uint32_t, x);
  u += 0x7fffu + ((u >> 16) & 1u);   // RNE; inputs are finite
  return (short)(u >> 16);
}

__device__ __forceinline__ f32x4 mfma_bf16(short8 a, short8 b, f32x4 c){
  return __builtin_amdgcn_mfma_f32_16x16x32_bf16(
      __builtin_bit_cast(bf16x8, a), __builtin_bit_cast(bf16x8, b), c, 0, 0, 0);
}

// async global->LDS, 16B per lane; LDS dest = wave-uniform base + lane*16
__device__ __forceinline__ void gload16(const short* g, short* l){
  __builtin_amdgcn_global_load_lds(
      (const __attribute__((address_space(1))) void*)g,
      (__attribute__((address_space(3))) void*)l, 16, 0, 0);
}

// ======== pre-pass: hs f32->bf16 + transpose Wq/Wk/Wv (Wo rides in k_gemm_qkv)
__global__ __launch_bounds__(256) void k_prep(const float* __restrict__ hs,
                                              short* __restrict__ hsb,
                                              const float* __restrict__ Wq, short* __restrict__ WqT,
                                              const float* __restrict__ Wk, short* __restrict__ WkT,
                                              const float* __restrict__ Wv, short* __restrict__ WvT){
  int bid = blockIdx.x;
  if (bid < 4096){
    int i = bid*256 + threadIdx.x;
    float4v v = ((const float4v* __restrict__)hs)[i];
    short4v o;
#pragma unroll
    for (int j=0;j<4;j++) o[j] = f2bf(v[j]);
    ((short4v* __restrict__)hsb)[i] = o;
    return;
  }
  bid -= 4096;
  const float* W; short* WT; int R, C, GX;
  if (bid < 4096)      { W = Wq; WT = WqT; R = HIDDEN; C = NHD; GX = 64; }
  else if (bid < 5120) { bid -= 4096; W = Wk; WT = WkT; R = HIDDEN; C = KVD; GX = 16; }
  else                 { bid -= 5120; W = Wv; WT = WvT; R = HIDDEN; C = KVD; GX = 16; }
  const int bx = bid % GX, by = bid / GX;
  __shared__ float tile[32][33];
  const int x = threadIdx.x & 31, y0 = threadIdx.x >> 5;
  const int c0 = bx*32, r0 = by*32;
#pragma unroll
  for (int yy=y0; yy<32; yy+=8) tile[yy][x] = W[(size_t)(r0+yy)*C + c0 + x];
  __syncthreads();
#pragma unroll
  for (int yy=y0; yy<32; yy+=8) WT[(size_t)(c0+yy)*R + r0 + x] = f2bf(tile[x][yy]);
}

// ==== 2-group in-block split-K GEMM cores ======================================
struct GemmIdx {
  int wid, r, g, wr, wc, kg, gtid, srow, c8, sx;
};
__device__ __forceinline__ GemmIdx gemm_idx(){
  GemmIdx ix;
  int tid = threadIdx.x, lane = tid&63;
  ix.kg = tid>>8; ix.gtid = tid&255;
  ix.wid = (tid>>6)&3; ix.r = lane&15; ix.g = lane>>4;
  ix.wr = ix.wid>>1; ix.wc = ix.wid&1;
  const int gt = ix.gtid;
  const int row0 = ((gt>>2) ^ (gt>>4)) & 1;
  ix.srow = (((gt>>3)<<1) | row0);
  ix.c8   = ((gt ^ (gt>>2) ^ (gt>>4)) & 1) | ((((gt>>1) ^ (gt>>3)) & 1) << 1);
  ix.sx   = (ix.r & 7) << 3;
  return ix;
}

__device__ __forceinline__ void compute128(const short* As, const short* Bs,
                                           f32x4 acc[4][4], const GemmIdx& ix){
  short8 af[4], bf[4];
#pragma unroll
  for (int m=0;m<4;m++)
    af[m] = *(const short8*)&As[((ix.wr*64 + m*16 + ix.r)*32 + ix.g*8) ^ ix.sx];
#pragma unroll
  for (int n=0;n<4;n++)
    bf[n] = *(const short8*)&Bs[((ix.wc*64 + n*16 + ix.r)*32 + ix.g*8) ^ ix.sx];
#pragma unroll
  for (int m=0;m<4;m++)
#pragma unroll
    for (int n=0;n<4;n++) acc[m][n] = mfma_bf16(af[m], bf[n], acc[m][n]);
}

__device__ __forceinline__ void red_groups(short* LDS, f32x4 acc[4][4], const GemmIdx& ix){
  __syncthreads();
  float* red = (float*)LDS;
  if (ix.kg){
#pragma unroll
    for (int m=0;m<4;m++)
#pragma unroll
      for (int n=0;n<4;n++)
#pragma unroll
        for (int j=0;j<4;j++)
          red[ix.wid*4096 + (m*16 + ix.g*4 + j)*64 + n*16 + ix.r] = acc[m][n][j];
  }
  __syncthreads();
  if (!ix.kg){
#pragma unroll
    for (int m=0;m<4;m++)
#pragma unroll
      for (int n=0;n<4;n++)
#pragma unroll
        for (int j=0;j<4;j++)
          acc[m][n][j] += red[ix.wid*4096 + (m*16 + ix.g*4 + j)*64 + n*16 + ix.r];
  }
}

// 2-buffer core (64 KB total), plain __syncthreads pipeline (r9-proven config).
template<int NKT>
__device__ __forceinline__ void gemm_core2(const short* __restrict__ A,
                                           const short* __restrict__ BT,
                                           int bm, int bn, short* LDS,
                                           f32x4 acc[4][4], const GemmIdx& ix){
  const int K = HIDDEN;
  const short* gA = A  + (size_t)(bm*128 + ix.srow)*K + ix.kg*(NKT*32) + ix.c8*8;
  const short* gB = BT + (size_t)(bn*128 + ix.srow)*K + ix.kg*(NKT*32) + ix.c8*8;
  short* L = LDS + ix.kg*16384;            // 2 bufs * 8192 shorts
  const int w = ix.gtid>>6;

#pragma unroll
  for (int m=0;m<4;m++)
#pragma unroll
    for (int n=0;n<4;n++) acc[m][n] = (f32x4){0.f,0.f,0.f,0.f};

  auto STAGE = [&](int buf, int kt){
    short* As_ = L + buf*8192;             // Bs_ = As_ + 4096
    gload16(gA + kt*32,                As_ + w*512);
    gload16(gA + (size_t)64*K + kt*32, As_ + 2048 + w*512);
    gload16(gB + kt*32,                As_ + 4096 + w*512);
    gload16(gB + (size_t)64*K + kt*32, As_ + 6144 + w*512);
  };

  STAGE(0, 0);
  __syncthreads();                         // buf0 ready
  for (int u=0; u<NKT/2; ++u){
    const int t = 2*u;
    if (t+1 < NKT) STAGE(1, t+1);          // in flight under compute
    compute128(L, L + 4096, acc, ix);
    __syncthreads();                       // buf1 landed; buf0 free
    if (t+2 < NKT) STAGE(0, t+2);
    compute128(L + 8192, L + 12288, acc, ix);
    __syncthreads();
  }
  red_groups(LDS, acc, ix);
}

// ==== 64x128-tile core: 2-group split-K, 3-buf counted-vmcnt, 72 KB ============
// For Wo: grid doubles to 512 blocks (2 blocks/CU) — cross-block overlap covers
// prologue/reduce tails that 1-block/CU left exposed. Wave owns 32x64 (acc[2][4]).
// Per thread per K-step: 3 gload16 (1 A + 2 B) -> counted waits vmcnt(6)/(3)/(0).
__device__ __forceinline__ void compute64(const short* As, const short* Bs,
                                          f32x4 acc[2][4], int wr2, int wc2,
                                          int r, int g){
  short8 af[2], bf[4];
#pragma unroll
  for (int m=0;m<2;m++)
    af[m] = *(const short8*)&As[(wr2*32 + m*16 + r)*32 + g*8];
#pragma unroll
  for (int n=0;n<4;n++)
    bf[n] = *(const short8*)&Bs[(wc2*64 + n*16 + r)*32 + g*8];
#pragma unroll
  for (int m=0;m<2;m++)
#pragma unroll
    for (int n=0;n<4;n++) acc[m][n] = mfma_bf16(af[m], bf[n], acc[m][n]);
}

template<int NKT>
__device__ __forceinline__ void gemm_core64(const short* __restrict__ A,
                                            const short* __restrict__ BT,
                                            int bm, int bn, short* LDS,
                                            f32x4 acc[2][4], const GemmIdx& ix){
  const int K = HIDDEN;
  // linear staging (no swizzle — r14: neutral): slot = gtid*8 shorts
  const int arow = ix.gtid>>2, ac8 = (ix.gtid&3)*8;
  const short* gA = A  + (size_t)(bm*64  + arow)*K + ix.kg*(NKT*32) + ac8;
  const short* gB = BT + (size_t)(bn*128 + arow)*K + ix.kg*(NKT*32) + ac8;
  short* L = LDS + ix.kg*18432;            // 3 bufs * 6144 shorts
  const int w = ix.gtid>>6;
  const int wr2 = ix.wid&1, wc2 = ix.wid>>1;

#pragma unroll
  for (int m=0;m<2;m++)
#pragma unroll
    for (int n=0;n<4;n++) acc[m][n] = (f32x4){0.f,0.f,0.f,0.f};

  auto STAGE = [&](int buf, int kt){
    short* As_ = L + buf*6144;             // A: 2048 shorts; B: 4096 at +2048
    gload16(gA + kt*32,                As_ + w*512);
    gload16(gB + kt*32,                As_ + 2048 + w*512);
    gload16(gB + (size_t)64*K + kt*32, As_ + 4096 + w*512);
  };

  STAGE(0, 0);
  STAGE(1, 1);
  int cur = 0;
  for (int t=0; t<NKT-2; ++t){
    int nxt = cur+2; if (nxt>=3) nxt-=3;
    STAGE(nxt, t+2);                       // in flight across the barriers
    WAITVM6();                             // buf-cur's 3 loads retired
    ABARRIER();
    compute64(L + cur*6144, L + cur*6144 + 2048, acc, wr2, wc2, ix.r, ix.g);
    ABARRIER();
    cur = (cur==2) ? 0 : cur+1;
  }
  WAITVM3();                               // t = NKT-2
  ABARRIER();
  compute64(L + cur*6144, L + cur*6144 + 2048, acc, wr2, wc2, ix.r, ix.g);
  ABARRIER();
  cur = (cur==2) ? 0 : cur+1;
  WAITVM0();                               // t = NKT-1 (final drain)
  ABARRIER();
  compute64(L + cur*6144, L + cur*6144 + 2048, acc, wr2, wc2, ix.r, ix.g);

  // cross-group reduce: [64][128] f32 = 32 KB (reuses pipeline LDS)
  __syncthreads();
  float* red = (float*)LDS;
  if (ix.kg){
#pragma unroll
    for (int m=0;m<2;m++)
#pragma unroll
      for (int n=0;n<4;n++)
#pragma unroll
        for (int j=0;j<4;j++)
          red[(wr2*32 + m*16 + ix.g*4 + j)*128 + wc2*64 + n*16 + ix.r] = acc[m][n][j];
  }
  __syncthreads();
  if (!ix.kg){
#pragma unroll
    for (int m=0;m<2;m++)
#pragma unroll
      for (int n=0;n<4;n++)
#pragma unroll
        for (int j=0;j<4;j++)
          acc[m][n][j] += red[(wr2*32 + m*16 + ix.g*4 + j)*128 + wc2*64 + n*16 + ix.r];
  }
}

// QKV GEMM, fused epilogues + Wo-transpose rider region (bn in [24,28)).
__global__ __launch_bounds__(512, 4) void k_gemm_qkv(const short* __restrict__ hsb,
                                                     const short* __restrict__ WqT,
                                                     const short* __restrict__ WkT,
                                                     const short* __restrict__ WvT,
                                                     const float* __restrict__ cosT,
                                                     const float* __restrict__ sinT,
                                                     const int* __restrict__ nm,
                                                     const float* __restrict__ Wo,
                                                     short* __restrict__ WoT,
                                                     short* __restrict__ Qb,
                                                     short* __restrict__ Kb,
                                                     short* __restrict__ VT,
                                                     short* __restrict__ VTs){
  __shared__ short LDS[32768];             // 64 KB: 2 groups x 2 bufs x 16 KB
  const int bn = blockIdx.x, bm = blockIdx.y;
  GemmIdx ix = gemm_idx();
  f32x4 acc[4][4];

  if (bn < 16){
    gemm_core2<32>(hsb, WqT + (size_t)bn*128*HIDDEN, bm, 0, LDS, acc, ix);
    if (ix.kg) return;
    const int h2 = bn*2 + ix.wc;
#pragma unroll
    for (int m=0;m<4;m++)
#pragma unroll
      for (int j=0;j<4;j++){
        const int s = bm*128 + ix.wr*64 + m*16 + ix.g*4 + j;
        const float* cr = cosT + s*64;
        const float* sr = sinT + s*64;
#pragma unroll
        for (int n=0;n<2;n++){
          const int d = n*16 + ix.r;
          float x1 = acc[m][n][j], x2 = acc[m][n+2][j];
          Qb[(size_t)s*NHD + h2*64 + d]      = f2bf((x1*cr[d]    - x2*sr[d])   *0.125f);
          Qb[(size_t)s*NHD + h2*64 + d + 32] = f2bf((x2*cr[d+32] + x1*sr[d+32])*0.125f);
        }
      }
  } else if (bn < 20){
    gemm_core2<32>(hsb, WkT + (size_t)(bn-16)*128*HIDDEN, bm, 0, LDS, acc, ix);
    if (ix.kg) return;
    const int h2 = (bn-16)*2 + ix.wc;
#pragma unroll
    for (int m=0;m<4;m++)
#pragma unroll
      for (int j=0;j<4;j++){
        const int s = bm*128 + ix.wr*64 + m*16 + ix.g*4 + j;
        const float* cr = cosT + s*64;
        const float* sr = sinT + s*64;
#pragma unroll
        for (int n=0;n<2;n++){
          const int d = n*16 + ix.r;
          float x1 = acc[m][n][j], x2 = acc[m][n+2][j];
          Kb[(size_t)s*KVD + h2*64 + d]      = f2bf(x1*cr[d]    - x2*sr[d]);
          Kb[(size_t)s*KVD + h2*64 + d + 32] = f2bf(x2*cr[d+32] + x1*sr[d+32]);
        }
      }
  } else if (bn < 24){
    gemm_core2<32>(hsb, WvT + (size_t)(bn-20)*128*HIDDEN, bm, 0, LDS, acc, ix);
    // V epilogue via LDS: Vt[128 d][136-stride s] bf16, then coalesced stores.
    const int bs  = nm[0] + 1;                 // power of 2 assumed (nm=3 -> 4)
    const int lbs = 31 - __clz(bs);
    const int d0  = (bn-20)*128;
    const int s0  = bm*128;
    short* Vt = LDS;
    __syncthreads();                           // reduce reads complete
    if (!ix.kg){
#pragma unroll
      for (int n=0;n<4;n++){
        const int dr = ix.wc*64 + n*16 + ix.r;
#pragma unroll
        for (int m=0;m<4;m++){
          const int sc_ = ix.wr*64 + m*16 + ix.g*4;
          short4v o;
#pragma unroll
          for (int j=0;j<4;j++) o[j] = f2bf(acc[m][n][j]);
          *(short4v*)&Vt[dr*136 + sc_] = o;
        }
      }
    }
    __syncthreads();
    const int tid = threadIdx.x;
#pragma unroll
    for (int it=0; it<4; ++it){
      const int row = tid>>2, c8 = (tid&3)*32 + it*8;
      *(short8*)&VT[(size_t)(d0+row)*S_LEN + s0 + c8] = *(short8*)&Vt[row*136 + c8];
    }
    const int cnt = 128 >> lbs;
    for (int e = tid; e < 128*cnt; e += 512){
      const int row = e >> (7 - lbs), c = e & (cnt - 1);
      VTs[(size_t)(d0+row)*S_LEN + (s0>>lbs) + c] = Vt[row*136 + (c<<lbs)];
    }
  } else {
    // Wo transpose rider
    const int bnt = bn - 24;
    float* tf = (float*)LDS;                   // 2 x 32 x 33 floats
    const int tid = threadIdx.x;
    const int half = tid >> 8;
    const int x = tid & 31, y0 = (tid >> 5) & 7;
    const int c0base = bnt*512, r0base = bm*128;
    for (int it=0; it<32; ++it){
      const int t = it*2 + half;               // 0..63
      const int c0 = c0base + (t & 15)*32;
      const int r0 = r0base + (t >> 4)*32;
      __syncthreads();
#pragma unroll
      for (int yy=y0; yy<32; yy+=8)
        tf[half*1056 + yy*33 + x] = Wo[(size_t)(r0+yy)*HIDDEN + c0 + x];
      __syncthreads();
#pragma unroll
      for (int yy=y0; yy<32; yy+=8)
        WoT[(size_t)(c0+yy)*NHD + r0 + x] = f2bf(tf[half*1056 + x*33 + yy]);
    }
  }
}

// Wo GEMM: 64x128 tile, 2-group split-K, 3-buf counted-vmcnt, 2 blocks/CU.
__global__ __launch_bounds__(512, 4) void k_gemm(const short* __restrict__ A,
                                                 const short* __restrict__ BT,
                                                 float* __restrict__ C, int Nc){
  __shared__ short LDS[36864];             // 72 KB: 2 groups x 3 bufs x 12 KB
  const int bn = blockIdx.x, bm = blockIdx.y;
  GemmIdx ix = gemm_idx();
  f32x4 acc[2][4];
  gemm_core64<32>(A, BT, bm, bn, LDS, acc, ix);
  if (ix.kg) return;
  const int wr2 = ix.wid&1, wc2 = ix.wid>>1;
#pragma unroll
  for (int m=0;m<2;m++)
#pragma unroll
    for (int n=0;n<4;n++)
#pragma unroll
      for (int j=0;j<4;j++)
        C[(size_t)(bm*64 + wr2*32 + m*16 + ix.g*4 + j)*Nc
          + bn*128 + wc2*64 + n*16 + ix.r] = acc[m][n][j];
}

// ======================= attention v6: 32 q-rows per 1-wave block ==============
#define BF16_ONE 16256   // 0x3F80

__device__ __forceinline__ void sm_pv2(f32x4 sc[2][4],
                                       f32x4 accl[2],
                                       f32x4 acc[2][4], short* Pw,
                                       const short* Vtile,   // [d][col], stride S_LEN
                                       int r, int g){
  const short8 ones = {BF16_ONE,BF16_ONE,BF16_ONE,BF16_ONE,
                       BF16_ONE,BF16_ONE,BF16_ONE,BF16_ONE};
#pragma unroll
  for (int m=0;m<2;m++)
#pragma unroll
    for (int n=0;n<4;n++)
#pragma unroll
      for (int j=0;j<4;j++)
        Pw[(m*16 + g*4 + j)*72 + n*16 + r] = f2bf(__expf(sc[m][n][j]));

  short8 pf[2][2];
#pragma unroll
  for (int m=0;m<2;m++){
    pf[m][0] = *(short8*)&Pw[(m*16 + r)*72 + g*8];
    pf[m][1] = *(short8*)&Pw[(m*16 + r)*72 + 32 + g*8];
    accl[m] = mfma_bf16(pf[m][0], ones, accl[m]);
    accl[m] = mfma_bf16(pf[m][1], ones, accl[m]);
  }
#pragma unroll
  for (int f=0;f<4;f++){
    short8 vf0 = *(const short8*)(Vtile + (size_t)(f*16 + r)*S_LEN + g*8);
    short8 vf1 = *(const short8*)(Vtile + (size_t)(f*16 + r)*S_LEN + 32 + g*8);
#pragma unroll
    for (int m=0;m<2;m++){
      acc[m][f] = mfma_bf16(pf[m][0], vf0, acc[m][f]);
      acc[m][f] = mfma_bf16(pf[m][1], vf1, acc[m][f]);
    }
  }
}

__global__ __launch_bounds__(64, 3) void k_attn4(const short* __restrict__ Qb,
                                                 const short* __restrict__ Kb,   // [S][KVD]
                                                 const short* __restrict__ VT,   // [KVD][S]
                                                 const short* __restrict__ VTs,  // [KVD][S/bs], stride S
                                                 const int* __restrict__ nm,
                                                 short* __restrict__ Ob){
  const int i  = gridDim.x - 1 - blockIdx.x;   // heavy q-sub-blocks first
  const int qs = i >> 5;                       // 32-row sub-block index, 0..63
  const int h  = i & 31;
  const int hk = h >> 2;
  const int bs = nm[0] + 1;                    // requires bs | 32

  const int lane = threadIdx.x;
  const int r = lane&15, g = lane>>4;

  __shared__ short Pw[32*72];

  const int qlo = qs*32;

  short8 qf[2][2];
#pragma unroll
  for (int m=0;m<2;m++){
    qf[m][0] = *(const short8*)(Qb + (size_t)(qlo + m*16 + r)*NHD + h*HD + g*8);
    qf[m][1] = *(const short8*)(Qb + (size_t)(qlo + m*16 + r)*NHD + h*HD + 32 + g*8);
  }

  f32x4 acc[2][4];
  f32x4 accl[2];
#pragma unroll
  for (int m=0;m<2;m++){
    accl[m] = (f32x4){0.f,0.f,0.f,0.f};
#pragma unroll
    for (int f=0;f<4;f++) acc[m][f] = (f32x4){0.f,0.f,0.f,0.f};
  }

  const short* Kg  = Kb  + hk*HD;
  const short* Vsg = VTs + (size_t)hk*HD*S_LEN;
  const short* Vdg = VT  + (size_t)hk*HD*S_LEN;

  // ---- column pass: keys k = bs*c for c < cmax (all causally allowed) ----
  const int cmax = qlo / bs;                   // exact (bs | 32)
  const int nct = (cmax + 63) >> 6;

  short8 kp[4][2];                             // prefetch buffer (one K tile)
  auto LOADK = [&](int cbase){
#pragma unroll
    for (int n=0;n<4;n++){
      const int key = bs*(cbase + n*16 + r);
      kp[n][0] = *(const short8*)(Kg + (size_t)key*KVD + g*8);
      kp[n][1] = *(const short8*)(Kg + (size_t)key*KVD + 32 + g*8);
    }
  };

  if (nct > 0) LOADK(0);
  for (int ct=0; ct<nct; ++ct){
    const int cbase = ct*64;
    f32x4 sc[2][4];
#pragma unroll
    for (int n=0;n<4;n++){
      const short8 kf0 = kp[n][0], kf1 = kp[n][1];
#pragma unroll
      for (int m=0;m<2;m++){
        f32x4 z = (f32x4){0.f,0.f,0.f,0.f};
        z = mfma_bf16(qf[m][0], kf0, z);
        sc[m][n] = mfma_bf16(qf[m][1], kf1, z);
      }
    }
    if (ct+1 < nct) LOADK(cbase + 64);         // prefetch under exp/P/PV
    if (cmax - cbase < 64){                    // partial last tile only
#pragma unroll
      for (int n=0;n<4;n++){
        if (cbase + n*16 + r >= cmax){
#pragma unroll
          for (int m=0;m<2;m++)
#pragma unroll
            for (int j=0;j<4;j++) sc[m][n][j] = -1e30f;
        }
      }
    }
    sm_pv2(sc, accl, acc, Pw, Vsg + cbase, r, g);
  }

  // ---- diag: the 32 keys [qlo, qlo+32) with the full mask ----
  {
    const short8 ones = {BF16_ONE,BF16_ONE,BF16_ONE,BF16_ONE,
                         BF16_ONE,BF16_ONE,BF16_ONE,BF16_ONE};
    f32x4 sd[2][2];                            // [m][n]
#pragma unroll
    for (int n=0;n<2;n++){
      const int key = qlo + n*16 + r;
      short8 kf0 = *(const short8*)(Kg + (size_t)key*KVD + g*8);
      short8 kf1 = *(const short8*)(Kg + (size_t)key*KVD + 32 + g*8);
#pragma unroll
      for (int m=0;m<2;m++){
        f32x4 z = (f32x4){0.f,0.f,0.f,0.f};
        z = mfma_bf16(qf[m][0], kf0, z);
        sd[m][n] = mfma_bf16(qf[m][1], kf1, z);
      }
    }
    int kdn[2]; bool kz[2];
#pragma unroll
    for (int n=0;n<2;n++){
      const int krel = n*16 + r;
      kdn[n] = krel / bs;
      kz[n]  = (krel % bs) == 0;
    }
#pragma unroll
    for (int m=0;m<2;m++)
#pragma unroll
      for (int j=0;j<4;j++){
        const int qrel = m*16 + g*4 + j;
        const int qd = qrel / bs;
#pragma unroll
        for (int n=0;n<2;n++){
          const int krel = n*16 + r;
          bool ok = (krel <= qrel) && (kz[n] || (kdn[n] == qd));
          sd[m][n][j] = ok ? sd[m][n][j] : -1e30f;
        }
      }
#pragma unroll
    for (int m=0;m<2;m++)
#pragma unroll
      for (int n=0;n<2;n++)
#pragma unroll
        for (int j=0;j<4;j++)
          Pw[(m*16 + g*4 + j)*72 + n*16 + r] = f2bf(__expf(sd[m][n][j]));

    short8 pf[2];
#pragma unroll
    for (int m=0;m<2;m++){
      pf[m] = *(short8*)&Pw[(m*16 + r)*72 + g*8];  // covers k=0..31
      accl[m] = mfma_bf16(pf[m], ones, accl[m]);
    }
#pragma unroll
    for (int f=0;f<4;f++){
      short8 vf = *(const short8*)(Vdg + (size_t)(f*16 + r)*S_LEN + qlo + g*8);
#pragma unroll
      for (int m=0;m<2;m++)
        acc[m][f] = mfma_bf16(pf[m], vf, acc[m][f]);
    }
  }

  // epilogue: O /= l, write bf16 (rows qlo + m*16 + g*4 + j)
#pragma unroll
  for (int m=0;m<2;m++)
#pragma unroll
    for (int j=0;j<4;j++){
      float inv = 1.f / accl[m][j];
      const int q = qlo + m*16 + g*4 + j;
#pragma unroll
      for (int f=0;f<4;f++)
        Ob[(size_t)q*NHD + h*HD + f*16 + r] = f2bf(acc[m][f][j]*inv);
    }
}

// ---------------- launch ----------------
extern "C" void kernel_launch(void* const* d_in, const int* in_sizes, int n_in,
                              void* d_out, int out_size, void* d_ws, size_t ws_size,
                              hipStream_t stream){
  const float* hs   = (const float*)d_in[0];
  const float* cosT = (const float*)d_in[1];
  const float* sinT = (const float*)d_in[2];
  const float* Wq   = (const float*)d_in[3];
  const float* Wk   = (const float*)d_in[4];
  const float* Wv   = (const float*)d_in[5];
  const float* Wo   = (const float*)d_in[6];
  const int*   nm   = (const int*)d_in[7];

  char* ws = (char*)d_ws;
  short* hsb  = (short*)(ws);                   // 8 MB
  short* WqT  = (short*)(ws + (8ull<<20));      // 8 MB
  short* WkT  = (short*)(ws + (16ull<<20));     // 2 MB
  short* WvT  = (short*)(ws + (18ull<<20));     // 2 MB
  short* WoT  = (short*)(ws + (20ull<<20));     // 8 MB
  short* Qb   = (short*)(ws + (28ull<<20));     // 8 MB
  short* Kb   = (short*)(ws + (36ull<<20));     // 2 MB
  short* VT   = (short*)(ws + (38ull<<20));     // 2 MB
  short* VTs  = (short*)(ws + (40ull<<20));     // 2 MB
  short* attnb= (short*)(ws + (42ull<<20));     // 8 MB
  float* out  = (float*)d_out;

  // pre-pass (hs cast + Wq/Wk/Wv transposes; Wo transpose rides in k_gemm_qkv)
  k_prep<<<dim3(10240), 256, 0, stream>>>(hs, hsb, Wq, WqT, Wk, WkT, Wv, WvT);

  // QKV GEMM (2-buf, 64 KB) + fused epilogues + Wo-transpose rider
  k_gemm_qkv<<<dim3(28, 16), 512, 0, stream>>>(hsb, WqT, WkT, WvT, cosT, sinT, nm,
                                               Wo, WoT, Qb, Kb, VT, VTs);

  // attention v6: 32 q-rows per 1-wave block + K-prefetch
  k_attn4<<<dim3((S_LEN/32)*NH), 64, 0, stream>>>(Qb, Kb, VT, VTs, nm, attnb);

  // Wo GEMM (64x128 tile, 3-buf counted-vmcnt, 2 blocks/CU)
  k_gemm<<<dim3(NHD/128, S_LEN/64), 512, 0, stream>>>(attnb, WoT, out, HIDDEN);
}

// Round 17
// 109.460 us; speedup vs baseline: 1.0463x; 1.0463x over previous
//
#include <hip/hip_runtime.h>
#include <hip/hip_bf16.h>
#include <stdint.h>

#define S_LEN  2048
#define HIDDEN 2048
#define NH     32
#define NKVH   8
#define HD     64
#define NHD    (NH*HD)    // 2048
#define KVD    (NKVH*HD)  // 512

typedef __attribute__((ext_vector_type(8))) short  short8;
typedef __attribute__((ext_vector_type(4))) short  short4v;
typedef __attribute__((ext_vector_type(4))) float  f32x4;
typedef __attribute__((ext_vector_type(4))) float  float4v;
typedef __attribute__((ext_vector_type(8))) __bf16 bf16x8;

// counted waits + barriers with memory clobber (rule #18 analog).
#define WAITVM8()  asm volatile("s_waitcnt vmcnt(8)" ::: "memory")
#define WAITVM4()  asm volatile("s_waitcnt vmcnt(4)" ::: "memory")
#define WAITVM0()  asm volatile("s_waitcnt vmcnt(0)" ::: "memory")
#define ABARRIER() asm volatile("s_barrier" ::: "memory")

__device__ __forceinline__ short f2bf(float x){
  uint32_t u = __builtin_bit_cast(uint32_t, x);
  u += 0x7fffu + ((u >> 16) & 1u);   // RNE; inputs are finite
  return (short)(u >> 16);
}

__device__ __forceinline__ f32x4 mfma_bf16(short8 a, short8 b, f32x4 c){
  return __builtin_amdgcn_mfma_f32_16x16x32_bf16(
      __builtin_bit_cast(bf16x8, a), __builtin_bit_cast(bf16x8, b), c, 0, 0, 0);
}

// async global->LDS, 16B per lane; LDS dest = wave-uniform base + lane*16
__device__ __forceinline__ void gload16(const short* g, short* l){
  __builtin_amdgcn_global_load_lds(
      (const __attribute__((address_space(1))) void*)g,
      (__attribute__((address_space(3))) void*)l, 16, 0, 0);
}

// ======== pre-pass: hs f32->bf16 + transpose Wq/Wk/Wv (Wo rides in k_gemm_qkv)
__global__ __launch_bounds__(256) void k_prep(const float* __restrict__ hs,
                                              short* __restrict__ hsb,
                                              const float* __restrict__ Wq, short* __restrict__ WqT,
                                              const float* __restrict__ Wk, short* __restrict__ WkT,
                                              const float* __restrict__ Wv, short* __restrict__ WvT){
  int bid = blockIdx.x;
  if (bid < 4096){
    int i = bid*256 + threadIdx.x;
    float4v v = ((const float4v* __restrict__)hs)[i];
    short4v o;
#pragma unroll
    for (int j=0;j<4;j++) o[j] = f2bf(v[j]);
    ((short4v* __restrict__)hsb)[i] = o;
    return;
  }
  bid -= 4096;
  const float* W; short* WT; int R, C, GX;
  if (bid < 4096)      { W = Wq; WT = WqT; R = HIDDEN; C = NHD; GX = 64; }
  else if (bid < 5120) { bid -= 4096; W = Wk; WT = WkT; R = HIDDEN; C = KVD; GX = 16; }
  else                 { bid -= 5120; W = Wv; WT = WvT; R = HIDDEN; C = KVD; GX = 16; }
  const int bx = bid % GX, by = bid / GX;
  __shared__ float tile[32][33];
  const int x = threadIdx.x & 31, y0 = threadIdx.x >> 5;
  const int c0 = bx*32, r0 = by*32;
#pragma unroll
  for (int yy=y0; yy<32; yy+=8) tile[yy][x] = W[(size_t)(r0+yy)*C + c0 + x];
  __syncthreads();
#pragma unroll
  for (int yy=y0; yy<32; yy+=8) WT[(size_t)(c0+yy)*R + r0 + x] = f2bf(tile[x][yy]);
}

// ==== 2-group in-block split-K GEMM cores ======================================
struct GemmIdx {
  int wid, r, g, wr, wc, kg, gtid, srow, c8, sx;
};
__device__ __forceinline__ GemmIdx gemm_idx(){
  GemmIdx ix;
  int tid = threadIdx.x, lane = tid&63;
  ix.kg = tid>>8; ix.gtid = tid&255;
  ix.wid = (tid>>6)&3; ix.r = lane&15; ix.g = lane>>4;
  ix.wr = ix.wid>>1; ix.wc = ix.wid&1;
  const int gt = ix.gtid;
  const int row0 = ((gt>>2) ^ (gt>>4)) & 1;
  ix.srow = (((gt>>3)<<1) | row0);
  ix.c8   = ((gt ^ (gt>>2) ^ (gt>>4)) & 1) | ((((gt>>1) ^ (gt>>3)) & 1) << 1);
  ix.sx   = (ix.r & 7) << 3;
  return ix;
}

__device__ __forceinline__ void compute128(const short* As, const short* Bs,
                                           f32x4 acc[4][4], const GemmIdx& ix){
  short8 af[4], bf[4];
#pragma unroll
  for (int m=0;m<4;m++)
    af[m] = *(const short8*)&As[((ix.wr*64 + m*16 + ix.r)*32 + ix.g*8) ^ ix.sx];
#pragma unroll
  for (int n=0;n<4;n++)
    bf[n] = *(const short8*)&Bs[((ix.wc*64 + n*16 + ix.r)*32 + ix.g*8) ^ ix.sx];
#pragma unroll
  for (int m=0;m<4;m++)
#pragma unroll
    for (int n=0;n<4;n++) acc[m][n] = mfma_bf16(af[m], bf[n], acc[m][n]);
}

__device__ __forceinline__ void red_groups(short* LDS, f32x4 acc[4][4], const GemmIdx& ix){
  __syncthreads();
  float* red = (float*)LDS;
  if (ix.kg){
#pragma unroll
    for (int m=0;m<4;m++)
#pragma unroll
      for (int n=0;n<4;n++)
#pragma unroll
        for (int j=0;j<4;j++)
          red[ix.wid*4096 + (m*16 + ix.g*4 + j)*64 + n*16 + ix.r] = acc[m][n][j];
  }
  __syncthreads();
  if (!ix.kg){
#pragma unroll
    for (int m=0;m<4;m++)
#pragma unroll
      for (int n=0;n<4;n++)
#pragma unroll
        for (int j=0;j<4;j++)
          acc[m][n][j] += red[ix.wid*4096 + (m*16 + ix.g*4 + j)*64 + n*16 + ix.r];
  }
}

// 2-buffer core (64 KB total), plain __syncthreads pipeline (r9-proven config).
template<int NKT>
__device__ __forceinline__ void gemm_core2(const short* __restrict__ A,
                                           const short* __restrict__ BT,
                                           int bm, int bn, short* LDS,
                                           f32x4 acc[4][4], const GemmIdx& ix){
  const int K = HIDDEN;
  const short* gA = A  + (size_t)(bm*128 + ix.srow)*K + ix.kg*(NKT*32) + ix.c8*8;
  const short* gB = BT + (size_t)(bn*128 + ix.srow)*K + ix.kg*(NKT*32) + ix.c8*8;
  short* L = LDS + ix.kg*16384;            // 2 bufs * 8192 shorts
  const int w = ix.gtid>>6;

#pragma unroll
  for (int m=0;m<4;m++)
#pragma unroll
    for (int n=0;n<4;n++) acc[m][n] = (f32x4){0.f,0.f,0.f,0.f};

  auto STAGE = [&](int buf, int kt){
    short* As_ = L + buf*8192;             // Bs_ = As_ + 4096
    gload16(gA + kt*32,                As_ + w*512);
    gload16(gA + (size_t)64*K + kt*32, As_ + 2048 + w*512);
    gload16(gB + kt*32,                As_ + 4096 + w*512);
    gload16(gB + (size_t)64*K + kt*32, As_ + 6144 + w*512);
  };

  STAGE(0, 0);
  __syncthreads();                         // buf0 ready
  for (int u=0; u<NKT/2; ++u){
    const int t = 2*u;
    if (t+1 < NKT) STAGE(1, t+1);          // in flight under compute
    compute128(L, L + 4096, acc, ix);
    __syncthreads();                       // buf1 landed; buf0 free
    if (t+2 < NKT) STAGE(0, t+2);
    compute128(L + 8192, L + 12288, acc, ix);
    __syncthreads();
  }
  red_groups(LDS, acc, ix);
}

// 3-buffer core (96 KB): stage-ahead-2, vmcnt(8) — for 1-block/CU kernels (Wo).
template<int NKT>
__device__ __forceinline__ void gemm_core3(const short* __restrict__ A,
                                           const short* __restrict__ BT,
                                           int bm, int bn, short* LDS,
                                           f32x4 acc[4][4], const GemmIdx& ix){
  const int K = HIDDEN;
  const short* gA = A  + (size_t)(bm*128 + ix.srow)*K + ix.kg*(NKT*32) + ix.c8*8;
  const short* gB = BT + (size_t)(bn*128 + ix.srow)*K + ix.kg*(NKT*32) + ix.c8*8;
  short* L = LDS + ix.kg*24576;            // 3 bufs * 8192 shorts
  const int w = ix.gtid>>6;

#pragma unroll
  for (int m=0;m<4;m++)
#pragma unroll
    for (int n=0;n<4;n++) acc[m][n] = (f32x4){0.f,0.f,0.f,0.f};

  auto STAGE = [&](int buf, int kt){
    short* As_ = L + buf*8192;
    gload16(gA + kt*32,                As_ + w*512);
    gload16(gA + (size_t)64*K + kt*32, As_ + 2048 + w*512);
    gload16(gB + kt*32,                As_ + 4096 + w*512);
    gload16(gB + (size_t)64*K + kt*32, As_ + 6144 + w*512);
  };

  STAGE(0, 0);
  STAGE(1, 1);
  int cur = 0;
  for (int t=0; t<NKT-2; ++t){
    int nxt = cur+2; if (nxt>=3) nxt-=3;
    STAGE(nxt, t+2);                       // in flight across the barriers
    WAITVM8();                             // oldest 4 (buf cur) retired
    ABARRIER();
    compute128(L + cur*8192, L + cur*8192 + 4096, acc, ix);
    ABARRIER();
    cur = (cur==2) ? 0 : cur+1;
  }
  WAITVM4();                               // t = NKT-2
  ABARRIER();
  compute128(L + cur*8192, L + cur*8192 + 4096, acc, ix);
  ABARRIER();
  cur = (cur==2) ? 0 : cur+1;
  WAITVM0();                               // t = NKT-1 (final drain)
  ABARRIER();
  compute128(L + cur*8192, L + cur*8192 + 4096, acc, ix);

  red_groups(LDS, acc, ix);
}

// QKV GEMM, fused epilogues + Wo-transpose rider region (bn in [24,28)).
__global__ __launch_bounds__(512, 4) void k_gemm_qkv(const short* __restrict__ hsb,
                                                     const short* __restrict__ WqT,
                                                     const short* __restrict__ WkT,
                                                     const short* __restrict__ WvT,
                                                     const float* __restrict__ cosT,
                                                     const float* __restrict__ sinT,
                                                     const int* __restrict__ nm,
                                                     const float* __restrict__ Wo,
                                                     short* __restrict__ WoT,
                                                     short* __restrict__ Qb,
                                                     short* __restrict__ Kb,
                                                     short* __restrict__ VT,
                                                     short* __restrict__ VTs){
  __shared__ short LDS[32768];             // 64 KB: 2 groups x 2 bufs x 16 KB
  const int bn = blockIdx.x, bm = blockIdx.y;
  GemmIdx ix = gemm_idx();
  f32x4 acc[4][4];

  if (bn < 16){
    gemm_core2<32>(hsb, WqT + (size_t)bn*128*HIDDEN, bm, 0, LDS, acc, ix);
    if (ix.kg) return;
    const int h2 = bn*2 + ix.wc;
#pragma unroll
    for (int m=0;m<4;m++)
#pragma unroll
      for (int j=0;j<4;j++){
        const int s = bm*128 + ix.wr*64 + m*16 + ix.g*4 + j;
        const float* cr = cosT + s*64;
        const float* sr = sinT + s*64;
#pragma unroll
        for (int n=0;n<2;n++){
          const int d = n*16 + ix.r;
          float x1 = acc[m][n][j], x2 = acc[m][n+2][j];
          Qb[(size_t)s*NHD + h2*64 + d]      = f2bf((x1*cr[d]    - x2*sr[d])   *0.125f);
          Qb[(size_t)s*NHD + h2*64 + d + 32] = f2bf((x2*cr[d+32] + x1*sr[d+32])*0.125f);
        }
      }
  } else if (bn < 20){
    gemm_core2<32>(hsb, WkT + (size_t)(bn-16)*128*HIDDEN, bm, 0, LDS, acc, ix);
    if (ix.kg) return;
    const int h2 = (bn-16)*2 + ix.wc;
#pragma unroll
    for (int m=0;m<4;m++)
#pragma unroll
      for (int j=0;j<4;j++){
        const int s = bm*128 + ix.wr*64 + m*16 + ix.g*4 + j;
        const float* cr = cosT + s*64;
        const float* sr = sinT + s*64;
#pragma unroll
        for (int n=0;n<2;n++){
          const int d = n*16 + ix.r;
          float x1 = acc[m][n][j], x2 = acc[m][n+2][j];
          Kb[(size_t)s*KVD + h2*64 + d]      = f2bf(x1*cr[d]    - x2*sr[d]);
          Kb[(size_t)s*KVD + h2*64 + d + 32] = f2bf(x2*cr[d+32] + x1*sr[d+32]);
        }
      }
  } else if (bn < 24){
    gemm_core2<32>(hsb, WvT + (size_t)(bn-20)*128*HIDDEN, bm, 0, LDS, acc, ix);
    // V epilogue via LDS: Vt[128 d][136-stride s] bf16, then coalesced stores.
    const int bs  = nm[0] + 1;                 // power of 2 assumed (nm=3 -> 4)
    const int lbs = 31 - __clz(bs);
    const int d0  = (bn-20)*128;
    const int s0  = bm*128;
    short* Vt = LDS;
    __syncthreads();                           // reduce reads complete
    if (!ix.kg){
#pragma unroll
      for (int n=0;n<4;n++){
        const int dr = ix.wc*64 + n*16 + ix.r;
#pragma unroll
        for (int m=0;m<4;m++){
          const int sc_ = ix.wr*64 + m*16 + ix.g*4;
          short4v o;
#pragma unroll
          for (int j=0;j<4;j++) o[j] = f2bf(acc[m][n][j]);
          *(short4v*)&Vt[dr*136 + sc_] = o;
        }
      }
    }
    __syncthreads();
    const int tid = threadIdx.x;
#pragma unroll
    for (int it=0; it<4; ++it){
      const int row = tid>>2, c8 = (tid&3)*32 + it*8;
      *(short8*)&VT[(size_t)(d0+row)*S_LEN + s0 + c8] = *(short8*)&Vt[row*136 + c8];
    }
    const int cnt = 128 >> lbs;
    for (int e = tid; e < 128*cnt; e += 512){
      const int row = e >> (7 - lbs), c = e & (cnt - 1);
      VTs[(size_t)(d0+row)*S_LEN + (s0>>lbs) + c] = Vt[row*136 + (c<<lbs)];
    }
  } else {
    // Wo transpose rider
    const int bnt = bn - 24;
    float* tf = (float*)LDS;                   // 2 x 32 x 33 floats
    const int tid = threadIdx.x;
    const int half = tid >> 8;
    const int x = tid & 31, y0 = (tid >> 5) & 7;
    const int c0base = bnt*512, r0base = bm*128;
    for (int it=0; it<32; ++it){
      const int t = it*2 + half;               // 0..63
      const int c0 = c0base + (t & 15)*32;
      const int r0 = r0base + (t >> 4)*32;
      __syncthreads();
#pragma unroll
      for (int yy=y0; yy<32; yy+=8)
        tf[half*1056 + yy*33 + x] = Wo[(size_t)(r0+yy)*HIDDEN + c0 + x];
      __syncthreads();
#pragma unroll
      for (int yy=y0; yy<32; yy+=8)
        WoT[(size_t)(c0+yy)*NHD + r0 + x] = f2bf(tf[half*1056 + x*33 + yy]);
    }
  }
}

// Wo GEMM: 128x128, 2-group split-K, 3-buffer counted-vmcnt (r15 best config).
__global__ __launch_bounds__(512, 4) void k_gemm(const short* __restrict__ A,
                                                 const short* __restrict__ BT,
                                                 float* __restrict__ C, int Nc){
  __shared__ short LDS[49152];             // 96 KB
  const int bn = blockIdx.x, bm = blockIdx.y;
  GemmIdx ix = gemm_idx();
  f32x4 acc[4][4];
  gemm_core3<32>(A, BT, bm, bn, LDS, acc, ix);
  if (ix.kg) return;
#pragma unroll
  for (int m=0;m<4;m++)
#pragma unroll
    for (int n=0;n<4;n++)
#pragma unroll
      for (int j=0;j<4;j++)
        C[(size_t)(bm*128 + ix.wr*64 + m*16 + ix.g*4 + j)*Nc
          + bn*128 + ix.wc*64 + n*16 + ix.r] = acc[m][n][j];
}

// ======================= attention v6: 32 q-rows per 1-wave block ==============
#define BF16_ONE 16256   // 0x3F80

__device__ __forceinline__ void sm_pv2(f32x4 sc[2][4],
                                       f32x4 accl[2],
                                       f32x4 acc[2][4], short* Pw,
                                       const short* Vtile,   // [d][col], stride S_LEN
                                       int r, int g){
  const short8 ones = {BF16_ONE,BF16_ONE,BF16_ONE,BF16_ONE,
                       BF16_ONE,BF16_ONE,BF16_ONE,BF16_ONE};
#pragma unroll
  for (int m=0;m<2;m++)
#pragma unroll
    for (int n=0;n<4;n++)
#pragma unroll
      for (int j=0;j<4;j++)
        Pw[(m*16 + g*4 + j)*72 + n*16 + r] = f2bf(__expf(sc[m][n][j]));

  short8 pf[2][2];
#pragma unroll
  for (int m=0;m<2;m++){
    pf[m][0] = *(short8*)&Pw[(m*16 + r)*72 + g*8];
    pf[m][1] = *(short8*)&Pw[(m*16 + r)*72 + 32 + g*8];
    accl[m] = mfma_bf16(pf[m][0], ones, accl[m]);
    accl[m] = mfma_bf16(pf[m][1], ones, accl[m]);
  }
#pragma unroll
  for (int f=0;f<4;f++){
    short8 vf0 = *(const short8*)(Vtile + (size_t)(f*16 + r)*S_LEN + g*8);
    short8 vf1 = *(const short8*)(Vtile + (size_t)(f*16 + r)*S_LEN + 32 + g*8);
#pragma unroll
    for (int m=0;m<2;m++){
      acc[m][f] = mfma_bf16(pf[m][0], vf0, acc[m][f]);
      acc[m][f] = mfma_bf16(pf[m][1], vf1, acc[m][f]);
    }
  }
}

__global__ __launch_bounds__(64, 3) void k_attn4(const short* __restrict__ Qb,
                                                 const short* __restrict__ Kb,   // [S][KVD]
                                                 const short* __restrict__ VT,   // [KVD][S]
                                                 const short* __restrict__ VTs,  // [KVD][S/bs], stride S
                                                 const int* __restrict__ nm,
                                                 short* __restrict__ Ob){
  const int i  = gridDim.x - 1 - blockIdx.x;   // heavy q-sub-blocks first
  const int qs = i >> 5;                       // 32-row sub-block index, 0..63
  const int h  = i & 31;
  const int hk = h >> 2;
  const int bs = nm[0] + 1;                    // requires bs | 32

  const int lane = threadIdx.x;
  const int r = lane&15, g = lane>>4;

  __shared__ short Pw[32*72];

  const int qlo = qs*32;

  short8 qf[2][2];
#pragma unroll
  for (int m=0;m<2;m++){
    qf[m][0] = *(const short8*)(Qb + (size_t)(qlo + m*16 + r)*NHD + h*HD + g*8);
    qf[m][1] = *(const short8*)(Qb + (size_t)(qlo + m*16 + r)*NHD + h*HD + 32 + g*8);
  }

  f32x4 acc[2][4];
  f32x4 accl[2];
#pragma unroll
  for (int m=0;m<2;m++){
    accl[m] = (f32x4){0.f,0.f,0.f,0.f};
#pragma unroll
    for (int f=0;f<4;f++) acc[m][f] = (f32x4){0.f,0.f,0.f,0.f};
  }

  const short* Kg  = Kb  + hk*HD;
  const short* Vsg = VTs + (size_t)hk*HD*S_LEN;
  const short* Vdg = VT  + (size_t)hk*HD*S_LEN;

  // ---- column pass: keys k = bs*c for c < cmax (all causally allowed) ----
  const int cmax = qlo / bs;                   // exact (bs | 32)
  const int nct = (cmax + 63) >> 6;

  short8 kp[4][2];                             // prefetch buffer (one K tile)
  auto LOADK = [&](int cbase){
#pragma unroll
    for (int n=0;n<4;n++){
      const int key = bs*(cbase + n*16 + r);
      kp[n][0] = *(const short8*)(Kg + (size_t)key*KVD + g*8);
      kp[n][1] = *(const short8*)(Kg + (size_t)key*KVD + 32 + g*8);
    }
  };

  if (nct > 0) LOADK(0);
  for (int ct=0; ct<nct; ++ct){
    const int cbase = ct*64;
    f32x4 sc[2][4];
#pragma unroll
    for (int n=0;n<4;n++){
      const short8 kf0 = kp[n][0], kf1 = kp[n][1];
#pragma unroll
      for (int m=0;m<2;m++){
        f32x4 z = (f32x4){0.f,0.f,0.f,0.f};
        z = mfma_bf16(qf[m][0], kf0, z);
        sc[m][n] = mfma_bf16(qf[m][1], kf1, z);
      }
    }
    if (ct+1 < nct) LOADK(cbase + 64);         // prefetch under exp/P/PV
    if (cmax - cbase < 64){                    // partial last tile only
#pragma unroll
      for (int n=0;n<4;n++){
        if (cbase + n*16 + r >= cmax){
#pragma unroll
          for (int m=0;m<2;m++)
#pragma unroll
            for (int j=0;j<4;j++) sc[m][n][j] = -1e30f;
        }
      }
    }
    sm_pv2(sc, accl, acc, Pw, Vsg + cbase, r, g);
  }

  // ---- diag: the 32 keys [qlo, qlo+32) with the full mask ----
  {
    const short8 ones = {BF16_ONE,BF16_ONE,BF16_ONE,BF16_ONE,
                         BF16_ONE,BF16_ONE,BF16_ONE,BF16_ONE};
    f32x4 sd[2][2];                            // [m][n]
#pragma unroll
    for (int n=0;n<2;n++){
      const int key = qlo + n*16 + r;
      short8 kf0 = *(const short8*)(Kg + (size_t)key*KVD + g*8);
      short8 kf1 = *(const short8*)(Kg + (size_t)key*KVD + 32 + g*8);
#pragma unroll
      for (int m=0;m<2;m++){
        f32x4 z = (f32x4){0.f,0.f,0.f,0.f};
        z = mfma_bf16(qf[m][0], kf0, z);
        sd[m][n] = mfma_bf16(qf[m][1], kf1, z);
      }
    }
    int kdn[2]; bool kz[2];
#pragma unroll
    for (int n=0;n<2;n++){
      const int krel = n*16 + r;
      kdn[n] = krel / bs;
      kz[n]  = (krel % bs) == 0;
    }
#pragma unroll
    for (int m=0;m<2;m++)
#pragma unroll
      for (int j=0;j<4;j++){
        const int qrel = m*16 + g*4 + j;
        const int qd = qrel / bs;
#pragma unroll
        for (int n=0;n<2;n++){
          const int krel = n*16 + r;
          bool ok = (krel <= qrel) && (kz[n] || (kdn[n] == qd));
          sd[m][n][j] = ok ? sd[m][n][j] : -1e30f;
        }
      }
#pragma unroll
    for (int m=0;m<2;m++)
#pragma unroll
      for (int n=0;n<2;n++)
#pragma unroll
        for (int j=0;j<4;j++)
          Pw[(m*16 + g*4 + j)*72 + n*16 + r] = f2bf(__expf(sd[m][n][j]));

    short8 pf[2];
#pragma unroll
    for (int m=0;m<2;m++){
      pf[m] = *(short8*)&Pw[(m*16 + r)*72 + g*8];  // covers k=0..31
      accl[m] = mfma_bf16(pf[m], ones, accl[m]);
    }
#pragma unroll
    for (int f=0;f<4;f++){
      short8 vf = *(const short8*)(Vdg + (size_t)(f*16 + r)*S_LEN + qlo + g*8);
#pragma unroll
      for (int m=0;m<2;m++)
        acc[m][f] = mfma_bf16(pf[m], vf, acc[m][f]);
    }
  }

  // epilogue: O /= l, write bf16 (rows qlo + m*16 + g*4 + j)
#pragma unroll
  for (int m=0;m<2;m++)
#pragma unroll
    for (int j=0;j<4;j++){
      float inv = 1.f / accl[m][j];
      const int q = qlo + m*16 + g*4 + j;
#pragma unroll
      for (int f=0;f<4;f++)
        Ob[(size_t)q*NHD + h*HD + f*16 + r] = f2bf(acc[m][f][j]*inv);
    }
}

// ---------------- launch ----------------
extern "C" void kernel_launch(void* const* d_in, const int* in_sizes, int n_in,
                              void* d_out, int out_size, void* d_ws, size_t ws_size,
                              hipStream_t stream){
  const float* hs   = (const float*)d_in[0];
  const float* cosT = (const float*)d_in[1];
  const float* sinT = (const float*)d_in[2];
  const float* Wq   = (const float*)d_in[3];
  const float* Wk   = (const float*)d_in[4];
  const float* Wv   = (const float*)d_in[5];
  const float* Wo   = (const float*)d_in[6];
  const int*   nm   = (const int*)d_in[7];

  char* ws = (char*)d_ws;
  short* hsb  = (short*)(ws);                   // 8 MB
  short* WqT  = (short*)(ws + (8ull<<20));      // 8 MB
  short* WkT  = (short*)(ws + (16ull<<20));     // 2 MB
  short* WvT  = (short*)(ws + (18ull<<20));     // 2 MB
  short* WoT  = (short*)(ws + (20ull<<20));     // 8 MB
  short* Qb   = (short*)(ws + (28ull<<20));     // 8 MB
  short* Kb   = (short*)(ws + (36ull<<20));     // 2 MB
  short* VT   = (short*)(ws + (38ull<<20));     // 2 MB
  short* VTs  = (short*)(ws + (40ull<<20));     // 2 MB
  short* attnb= (short*)(ws + (42ull<<20));     // 8 MB
  float* out  = (float*)d_out;

  // pre-pass (hs cast + Wq/Wk/Wv transposes; Wo transpose rides in k_gemm_qkv)
  k_prep<<<dim3(10240), 256, 0, stream>>>(hs, hsb, Wq, WqT, Wk, WkT, Wv, WvT);

  // QKV GEMM (2-buf, 64 KB) + fused epilogues + Wo-transpose rider
  k_gemm_qkv<<<dim3(28, 16), 512, 0, stream>>>(hsb, WqT, WkT, WvT, cosT, sinT, nm,
                                               Wo, WoT, Qb, Kb, VT, VTs);

  // attention v6: 32 q-rows per 1-wave block + K-prefetch
  k_attn4<<<dim3((S_LEN/32)*NH), 64, 0, stream>>>(Qb, Kb, VT, VTs, nm, attnb);

  // Wo GEMM (128x128, 3-buf counted-vmcnt, 96 KB — r15 best config)
  k_gemm<<<dim3(NHD/128, S_LEN/128), 512, 0, stream>>>(attnb, WoT, out, HIDDEN);
}